// Round 20
// baseline (223.885 us; speedup 1.0000x reference)
//
#include <hip/hip_runtime.h>
#include <hip/hip_bf16.h>
#include <math.h>

#define NB_B 256
#define NB_S 50
#define NB_NB 8
#define NB_D 128
#define NB_NITEMS 100000

#define C_RZ (-1.442695041f)   // -log2(e): sigmoid arg prescale
#define C_N (2.885390082f)     // 2*log2(e): tanh arg prescale

typedef __attribute__((ext_vector_type(8))) short short8;   // 8 x bf16 (4 VGPR)
typedef __attribute__((ext_vector_type(4))) float f32x4;    // MFMA acc
typedef unsigned int uint;
typedef unsigned short ushort;

// fp32 -> bf16 round-to-nearest-even
__device__ __forceinline__ ushort f2bf(float f) {
  union { float f; uint u; } v;
  v.f = f;
  return (ushort)((v.u + 0x7fffu + ((v.u >> 16) & 1u)) >> 16);
}
__device__ __forceinline__ uint packbf(float a, float b) {
  return (uint)f2bf(a) | ((uint)f2bf(b) << 16);
}
__device__ __forceinline__ float bflo(uint u) {
  union { uint u; float f; } v; v.u = u << 16; return v.f;
}
__device__ __forceinline__ float bfhi(uint u) {
  union { uint u; float f; } v; v.u = u & 0xffff0000u; return v.f;
}
__device__ __forceinline__ float bf2f(ushort u) {
  union { uint u; float f; } v; v.u = (uint)u << 16; return v.f;
}
__device__ __forceinline__ void unpack8(uint4 u, float* f) {
  f[0] = bflo(u.x); f[1] = bfhi(u.x);
  f[2] = bflo(u.y); f[3] = bfhi(u.y);
  f[4] = bflo(u.z); f[5] = bfhi(u.z);
  f[6] = bflo(u.w); f[7] = bfhi(u.w);
}

// ---------------- fused prep: casts + transposes + GI bias + flattened KG ids ----------------
__device__ __forceinline__ void castf_body(const float* __restrict__ src,
                                           uint* __restrict__ dst, int i, int n8) {
  if (i >= n8) return;
  float4 a = ((const float4*)src)[2 * i];
  float4 b = ((const float4*)src)[2 * i + 1];
  uint4 o;
  o.x = packbf(a.x, a.y);
  o.y = packbf(a.z, a.w);
  o.z = packbf(b.x, b.y);
  o.w = packbf(b.z, b.w);
  ((uint4*)dst)[i] = o;
}
template <int CO, bool SCALED>
__device__ __forceinline__ void castT_body(const float* __restrict__ W,
                                           ushort* __restrict__ WT, int idx) {
  if (idx >= 128 * CO) return;
  int n = idx >> 7, k = idx & 127;
  float v = W[(size_t)k * CO + n];
  if (SCALED) v *= (n < 256 ? C_RZ : C_N);
  WT[idx] = f2bf(v);
}
__global__ __launch_bounds__(256) void prep_kernel(
    const float* __restrict__ item_emb, const float* __restrict__ rel_emb,
    const float* __restrict__ Wt, const float* __restrict__ Wih,
    const float* __restrict__ Whh, const float* __restrict__ W2,
    const float* __restrict__ bih, const float* __restrict__ bhh,
    const int* __restrict__ h_iids, const int* __restrict__ adj_e,
    const int* __restrict__ adj_r, uint* __restrict__ EMB_BF,
    uint* __restrict__ REL_BF, ushort* __restrict__ WtT,
    ushort* __restrict__ WihT, ushort* __restrict__ WhhT,
    ushort* __restrict__ W2T, float* __restrict__ GIBIAS,
    int* __restrict__ E0, int* __restrict__ E2, int* __restrict__ RK,
    int* __restrict__ RK1) {
  int bx = blockIdx.x, tid = threadIdx.x;
  if (bx < 6250) {
    castf_body(item_emb, EMB_BF, bx * 256 + tid, 1600000);
  } else if (bx < 6263) {
    castf_body(rel_emb, REL_BF, (bx - 6250) * 256 + tid, 3200);
  } else if (bx < 6327) {
    castT_body<128, false>(Wt, WtT, (bx - 6263) * 256 + tid);
  } else if (bx < 6519) {
    castT_body<384, true>(Wih, WihT, (bx - 6327) * 256 + tid);
  } else if (bx < 6711) {
    castT_body<384, true>(Whh, WhhT, (bx - 6519) * 256 + tid);
  } else if (bx < 6775) {
    castT_body<128, false>(W2, W2T, (bx - 6711) * 256 + tid);
  } else if (bx < 6776) {
    if (tid < 256) GIBIAS[tid] = C_RZ * (bih[tid] + bhh[tid]);
  } else if (bx < 6777) {
    int idx = 256 + tid;
    if (idx < 384) GIBIAS[idx] = C_N * bih[idx];
  } else if (bx < 7177) {
    // flatten hop0 graph walk: E0[p], E2[p*8+k], RK[p*8+k]
    int p = (bx - 6777) * 256 + tid;
    if (p < NB_B * NB_S * NB_NB) {
      int b = p / (NB_S * NB_NB);
      int m = p % (NB_S * NB_NB);
      int h = h_iids[b * NB_S + (m >> 3)];
      int e = adj_e[h * NB_NB + (m & 7)];
      E0[p] = e;
      int4 ea = ((const int4*)(adj_e + (size_t)e * 8))[0];
      int4 eb = ((const int4*)(adj_e + (size_t)e * 8))[1];
      int4 ra = ((const int4*)(adj_r + (size_t)e * 8))[0];
      int4 rb = ((const int4*)(adj_r + (size_t)e * 8))[1];
      ((int4*)(E2 + (size_t)p * 8))[0] = ea;
      ((int4*)(E2 + (size_t)p * 8))[1] = eb;
      ((int4*)(RK + (size_t)p * 8))[0] = ra;
      ((int4*)(RK + (size_t)p * 8))[1] = rb;
    }
  } else {
    // hop1 rel ids: RK1[p*8+k]
    int p = (bx - 7177) * 256 + tid;
    if (p < NB_B * NB_S) {
      int e = h_iids[p];
      int4 ra = ((const int4*)(adj_r + (size_t)e * 8))[0];
      int4 rb = ((const int4*)(adj_r + (size_t)e * 8))[1];
      ((int4*)(RK1 + (size_t)p * 8))[0] = ra;
      ((int4*)(RK1 + (size_t)p * 8))[1] = rb;
    }
  }
}

// ---------------- hop pair: 16-lane group, 8 dims/lane, flattened ids ----------------
__device__ __forceinline__ uint4 hop_pair4(
    int e_self, int q, int p, const int* __restrict__ E2d,
    const int* __restrict__ RKd, const uint* __restrict__ embB,
    const uint* __restrict__ relB, const uint* __restrict__ neibB,
    const float* __restrict__ Wa, float* __restrict__ alds) {
  uint4 us = ((const uint4*)(embB + (size_t)e_self * 64))[q];
  float s[8], wa[8], sw[8];
  unpack8(us, s);
  *(float4*)&wa[0] = ((const float4*)Wa)[q * 2];
  *(float4*)&wa[4] = ((const float4*)Wa)[q * 2 + 1];
#pragma unroll
  for (int d = 0; d < 8; d++) sw[d] = s[d] * wa[d];

  int4 ra = ((const int4*)(RKd + (size_t)p * 8))[0];
  int4 rb = ((const int4*)(RKd + (size_t)p * 8))[1];
  int rk[8] = {ra.x, ra.y, ra.z, ra.w, rb.x, rb.y, rb.z, rb.w};

  uint4 nbp[8];
  if (neibB == nullptr) {
    int4 ea = ((const int4*)(E2d + (size_t)p * 8))[0];
    int4 eb = ((const int4*)(E2d + (size_t)p * 8))[1];
    int e2[8] = {ea.x, ea.y, ea.z, ea.w, eb.x, eb.y, eb.z, eb.w};
#pragma unroll
    for (int k = 0; k < 8; k++)
      nbp[k] = ((const uint4*)(embB + (size_t)e2[k] * 64))[q];
  } else {
#pragma unroll
    for (int k = 0; k < 8; k++)
      nbp[k] = ((const uint4*)(neibB + ((size_t)p * 8 + k) * 64))[q];
  }

  float t[8];
#pragma unroll
  for (int k = 0; k < 8; k++) {
    uint4 ur = ((const uint4*)(relB + (size_t)rk[k] * 64))[q];
    float rr[8], nb[8];
    unpack8(ur, rr);
    unpack8(nbp[k], nb);
    float tt = 0.f;
#pragma unroll
    for (int d = 0; d < 8; d++) tt = fmaf(sw[d] * rr[d], nb[d], tt);
    t[k] = tt;
  }

  // multi-value halving butterfly within 16 lanes: 8 values -> 1 per lane
  bool b0 = (q & 1), b1 = (q & 2), b2 = (q & 4);
  float a4[4];
#pragma unroll
  for (int i = 0; i < 4; i++) {
    float send = b0 ? t[i] : t[4 + i];
    float recv = __shfl_xor(send, 1);
    a4[i] = (b0 ? t[4 + i] : t[i]) + recv;
  }
  float a2[2];
#pragma unroll
  for (int i = 0; i < 2; i++) {
    float send = b1 ? a4[i] : a4[2 + i];
    float recv = __shfl_xor(send, 2);
    a2[i] = (b1 ? a4[2 + i] : a4[i]) + recv;
  }
  float send1 = b2 ? a2[0] : a2[1];
  float recv1 = __shfl_xor(send1, 4);
  float c = (b2 ? a2[1] : a2[0]) + recv1;
  c += __shfl_xor(c, 8);  // att[k*], k* = (q&1)*4 + (q&2) + ((q&4)>>2)

  // softmax over 8 k-classes (|att|<=~0.04: no max-subtraction needed)
  float e = __expf(c);
  float den = e;
  den += __shfl_xor(den, 1);
  den += __shfl_xor(den, 2);
  den += __shfl_xor(den, 4);
  float alpha = e * __builtin_amdgcn_rcpf(den);

  // broadcast alphas via per-group LDS slot (wave-synchronous)
  int kstar = (q & 1) * 4 + (q & 2) + ((q & 4) >> 2);
  if (q < 8) alds[kstar] = alpha;
  asm volatile("s_waitcnt lgkmcnt(0)" ::: "memory");
  float a8[8];
  *(float4*)&a8[0] = ((const float4*)alds)[0];
  *(float4*)&a8[4] = ((const float4*)alds)[1];

  float x[8];
#pragma unroll
  for (int d = 0; d < 8; d++) x[d] = s[d];
#pragma unroll
  for (int k = 0; k < 8; k++) {
    float nb[8];
    unpack8(nbp[k], nb);
#pragma unroll
    for (int d = 0; d < 8; d++) x[d] = fmaf(a8[k], nb[d], x[d]);
  }
  uint4 o;
  o.x = packbf(x[0], x[1]);
  o.y = packbf(x[2], x[3]);
  o.z = packbf(x[4], x[5]);
  o.w = packbf(x[6], x[7]);
  return o;
}

// ---------------- fused hop0 + lin0: 16 pairs/block, fully flattened ids ----------------
__global__ __launch_bounds__(256) void hoplin_kernel(
    const int* __restrict__ E0, const int* __restrict__ E2,
    const int* __restrict__ RK, const uint* __restrict__ embB,
    const uint* __restrict__ relB, const float* __restrict__ Wa,
    const ushort* __restrict__ WtT, const float* __restrict__ bt,
    ushort* __restrict__ NEIB) {
  __shared__ ushort X0s[16 * 128];  // XOR-swizzled
  __shared__ float als[16][8];
  const int bx = blockIdx.x;
  const int wv = threadIdx.x >> 6, ln = threadIdx.x & 63;
  const int g = ln >> 4, q = ln & 15;
  const int lp = wv * 4 + g;  // local pair 0..15
  const int p = bx * 16 + lp;

  int e_self = E0[p];
  uint4 o = hop_pair4(e_self, q, p, E2, RK, embB, relB, nullptr, Wa, als[lp]);
  {
    int byte = (lp * 256 + q * 16) ^ ((lp & 7) << 4);
    *(uint4*)((char*)X0s + byte) = o;
  }
  __syncthreads();

  // MFMA: NEIB[16 rows][128] = X0s @ WtT^T + bt; wave wv covers cols [32wv,32wv+32)
  const int lr = ln & 15, lg = ln >> 4;
  short8 afr[4];
#pragma unroll
  for (int kf = 0; kf < 4; kf++) {
    int byte = (lr * 256 + lg * 16 + kf * 64) ^ ((lr & 7) << 4);
    afr[kf] = *(const short8*)((const char*)X0s + byte);
  }
  f32x4 acc[2] = {};
#pragma unroll
  for (int nf = 0; nf < 2; nf++) {
    int n = (wv * 2 + nf) * 16 + lr;
    const ushort* bb = WtT + (size_t)n * 128 + lg * 8;
#pragma unroll
    for (int kf = 0; kf < 4; kf++) {
      short8 bv = *(const short8*)(bb + kf * 32);
      acc[nf] = __builtin_amdgcn_mfma_f32_16x16x32_bf16(afr[kf], bv, acc[nf],
                                                        0, 0, 0);
    }
  }
#pragma unroll
  for (int nf = 0; nf < 2; nf++) {
    int n = (wv * 2 + nf) * 16 + lr;
    float bv = bt[n];
#pragma unroll
    for (int r = 0; r < 4; r++) {
      int mg = bx * 16 + lg * 4 + r;
      NEIB[(size_t)mg * 128 + n] = f2bf(acc[nf][r] + bv);
    }
  }
}

// ---------------- fused hop1 + SEQ GEMM + GI GEMM ----------------
__global__ __launch_bounds__(256) void hopgi_kernel(
    const int* __restrict__ h_iids, const int* __restrict__ RK1,
    const uint* __restrict__ embB, const uint* __restrict__ relB,
    const uint* __restrict__ neibB, const float* __restrict__ Wa,
    const ushort* __restrict__ WtT, const float* __restrict__ bt,
    const ushort* __restrict__ WihT, const float* __restrict__ GIBIAS,
    float* __restrict__ GI) {
  __shared__ ushort X1s[16 * 128];  // XOR-swizzled
  __shared__ ushort SEQs[16 * 128]; // XOR-swizzled
  __shared__ float als[16][8];
  const int wv = threadIdx.x >> 6, ln = threadIdx.x & 63;
  const int g = ln >> 4, q = ln & 15;
  const int lp = wv * 4 + g;  // local pair 0..15
  const int p = blockIdx.x * 16 + lp;

  int e_self = h_iids[p];
  uint4 o = hop_pair4(e_self, q, p, nullptr, RK1, embB, relB, neibB, Wa, als[lp]);
  {
    int byte = (lp * 256 + q * 16) ^ ((lp & 7) << 4);
    *(uint4*)((char*)X1s + byte) = o;
  }
  __syncthreads();

  const int lr = ln & 15, lg = ln >> 4;
  // phase 2: SEQ = X1 @ WtT + bt; wave covers cols [wv*32, wv*32+32)
  {
    short8 afr[4];
#pragma unroll
    for (int kf = 0; kf < 4; kf++) {
      int byte = (lr * 256 + lg * 16 + kf * 64) ^ ((lr & 7) << 4);
      afr[kf] = *(const short8*)((const char*)X1s + byte);
    }
    f32x4 acc[2] = {};
#pragma unroll
    for (int nf = 0; nf < 2; nf++) {
      int n = (wv * 2 + nf) * 16 + lr;
      const ushort* bb = WtT + (size_t)n * 128 + lg * 8;
#pragma unroll
      for (int kf = 0; kf < 4; kf++) {
        short8 b = *(const short8*)(bb + kf * 32);
        acc[nf] = __builtin_amdgcn_mfma_f32_16x16x32_bf16(afr[kf], b, acc[nf],
                                                          0, 0, 0);
      }
    }
#pragma unroll
    for (int nf = 0; nf < 2; nf++) {
      int n = (wv * 2 + nf) * 16 + lr;
      float bv = bt[n];
#pragma unroll
      for (int r = 0; r < 4; r++) {
        int m = lg * 4 + r;
        int byte = (m * 256 + n * 2) ^ ((m & 7) << 4);
        *(ushort*)((char*)SEQs + byte) = f2bf(acc[nf][r] + bv);
      }
    }
  }
  __syncthreads();

  // phase 3: GI = SEQ @ WihT + GIBIAS; wave covers cols [wv*96, wv*96+96)
  {
    short8 sfr[4];
#pragma unroll
    for (int kf = 0; kf < 4; kf++) {
      int byte = (lr * 256 + lg * 16 + kf * 64) ^ ((lr & 7) << 4);
      sfr[kf] = *(const short8*)((const char*)SEQs + byte);
    }
#pragma unroll
    for (int i = 0; i < 6; i++) {
      int n = (wv * 6 + i) * 16 + lr;
      const ushort* bb = WihT + (size_t)n * 128 + lg * 8;
      f32x4 a2 = {};
#pragma unroll
      for (int kf = 0; kf < 4; kf++) {
        short8 b = *(const short8*)(bb + kf * 32);
        a2 = __builtin_amdgcn_mfma_f32_16x16x32_bf16(sfr[kf], b, a2, 0, 0, 0);
      }
      float bv = GIBIAS[n];
#pragma unroll
      for (int r = 0; r < 4; r++) {
        int m = lg * 4 + r;
        GI[(size_t)(blockIdx.x * 16 + m) * 384 + n] = a2[r] + bv;
      }
    }
  }
}

// ---------------- GRU: 2 independent 16-batch groups per block ----------------
// R19 PM: gru ~50-57us, chain-latency bound, 1 block/CU with lockstep waves ->
// nothing overlaps the serial chain. Fix: 8 blocks x 32 batches (2 groups),
// both groups' {ds_read, MFMA, gates} interleaved between ONE barrier pair ->
// 2x ILP on every pipe at ~same critical path. Whh frags shared. Depth-2 GI
// register pipeline per group (3 named buffers; steps are longer now).
__global__ __launch_bounds__(512) void gru_mfma_kernel(
    const float* __restrict__ GI, const ushort* __restrict__ WhhT_bf,
    const float* __restrict__ bhh, ushort* __restrict__ OUTB) {
  const int b0 = blockIdx.x * 32;  // group A: b0.., group B: b0+16..
  const int tid = threadIdx.x;
  const int w = tid >> 6, ln = tid & 63;
  const int lr = ln & 15, lg = ln >> 4;
  const int j = w * 16 + lr;

  __shared__ ushort h0[2 * 2048];  // [grp*2048 + ...], XOR-swizzled, dbuf
  __shared__ ushort h1[2 * 2048];

  short8 bfr[3][4];  // shared across both groups (same j)
#pragma unroll
  for (int g = 0; g < 3; g++) {
    const ushort* bb = WhhT_bf + (size_t)(g * 128 + j) * 128 + lg * 8;
#pragma unroll
    for (int kf = 0; kf < 4; kf++) bfr[g][kf] = *(const short8*)(bb + kf * 32);
  }
  const float bhn = C_N * bhh[256 + j];

  float hrA[4] = {0.f, 0.f, 0.f, 0.f};
  float hrB[4] = {0.f, 0.f, 0.f, 0.f};

  {  // zero h0 (both groups)
    uint* hz = (uint*)h0;
#pragma unroll
    for (int i = tid; i < 2048; i += 512) hz[i] = 0;
  }
  __syncthreads();

  // GI pipeline depth 2: 3 named buffers per group
  float gA0[4][3], gA1[4][3], gA2[4][3];
  float gB0[4][3], gB1[4][3], gB2[4][3];
#pragma unroll
  for (int r = 0; r < 4; r++) {
    const float* a0 = GI + ((size_t)(b0 + lg * 4 + r) * NB_S + 0) * 384 + j;
    gA0[r][0] = a0[0]; gA0[r][1] = a0[128]; gA0[r][2] = a0[256];
    const float* a1 = GI + ((size_t)(b0 + lg * 4 + r) * NB_S + 1) * 384 + j;
    gA1[r][0] = a1[0]; gA1[r][1] = a1[128]; gA1[r][2] = a1[256];
    const float* c0 = GI + ((size_t)(b0 + 16 + lg * 4 + r) * NB_S + 0) * 384 + j;
    gB0[r][0] = c0[0]; gB0[r][1] = c0[128]; gB0[r][2] = c0[256];
    const float* c1 = GI + ((size_t)(b0 + 16 + lg * 4 + r) * NB_S + 1) * 384 + j;
    gB1[r][0] = c1[0]; gB1[r][1] = c1[128]; gB1[r][2] = c1[256];
  }

  auto STEP2 = [&](int t, ushort* hR, ushort* hW, float (&curA)[4][3],
                   float (&preA)[4][3], float (&curB)[4][3],
                   float (&preB)[4][3]) {
    // prefetch GI for t+2, both groups
    if (t + 2 < NB_S) {
#pragma unroll
      for (int r = 0; r < 4; r++) {
        const float* a = GI + ((size_t)(b0 + lg * 4 + r) * NB_S + (t + 2)) * 384 + j;
        preA[r][0] = a[0]; preA[r][1] = a[128]; preA[r][2] = a[256];
        const float* c =
            GI + ((size_t)(b0 + 16 + lg * 4 + r) * NB_S + (t + 2)) * 384 + j;
        preB[r][0] = c[0]; preB[r][1] = c[128]; preB[r][2] = c[256];
      }
    }
    __builtin_amdgcn_sched_barrier(0);  // pin load issue at top of step
    short8 afrA[4], afrB[4];
#pragma unroll
    for (int kf = 0; kf < 4; kf++) {
      int byte = (lr * 256 + kf * 64 + lg * 16) ^ ((lr & 7) << 4);
      afrA[kf] = *(const short8*)((const char*)hR + byte);
      afrB[kf] = *(const short8*)((const char*)hR + 4096 + byte);
    }
    f32x4 accA[3] = {}, accB[3] = {};
#pragma unroll
    for (int g = 0; g < 3; g++)
#pragma unroll
      for (int kf = 0; kf < 4; kf++) {
        accA[g] = __builtin_amdgcn_mfma_f32_16x16x32_bf16(afrA[kf], bfr[g][kf],
                                                          accA[g], 0, 0, 0);
        accB[g] = __builtin_amdgcn_mfma_f32_16x16x32_bf16(afrB[kf], bfr[g][kf],
                                                          accB[g], 0, 0, 0);
      }
#pragma unroll
    for (int r = 0; r < 4; r++) {
      int b = lg * 4 + r;
      // group A
      float rgA = __builtin_amdgcn_rcpf(
          1.f + __builtin_amdgcn_exp2f(curA[r][0] + accA[0][r]));
      float zeA = __builtin_amdgcn_exp2f(curA[r][1] + accA[1][r]);
      float xpA = curA[r][2] + rgA * (bhn + accA[2][r]);
      float e2A = __builtin_amdgcn_exp2f(xpA);
      float nA = 1.f - 2.f * __builtin_amdgcn_rcpf(e2A + 1.f);
      float h2A = nA + (hrA[r] - nA) * __builtin_amdgcn_rcpf(1.f + zeA);
      hrA[r] = h2A;
      ushort hbA = f2bf(h2A);
      OUTB[((size_t)(b0 + b) * NB_S + t) * 128 + j] = hbA;
      int byte = (b * 256 + j * 2) ^ ((b & 7) << 4);
      *(ushort*)((char*)hW + byte) = hbA;
      // group B
      float rgB = __builtin_amdgcn_rcpf(
          1.f + __builtin_amdgcn_exp2f(curB[r][0] + accB[0][r]));
      float zeB = __builtin_amdgcn_exp2f(curB[r][1] + accB[1][r]);
      float xpB = curB[r][2] + rgB * (bhn + accB[2][r]);
      float e2B = __builtin_amdgcn_exp2f(xpB);
      float nB = 1.f - 2.f * __builtin_amdgcn_rcpf(e2B + 1.f);
      float h2B = nB + (hrB[r] - nB) * __builtin_amdgcn_rcpf(1.f + zeB);
      hrB[r] = h2B;
      ushort hbB = f2bf(h2B);
      OUTB[((size_t)(b0 + 16 + b) * NB_S + t) * 128 + j] = hbB;
      *(ushort*)((char*)hW + 4096 + byte) = hbB;
    }
    asm volatile("s_waitcnt lgkmcnt(0)" ::: "memory");
    __builtin_amdgcn_s_barrier();  // h visible; global ops stay in flight
  };

  // 48 steps in 16 groups of 3 (buffer rotation period 3), then 2 peeled.
  for (int g3 = 0; g3 < 16; g3++) {
    int t = g3 * 3;  // parity of t == parity of g3
    ushort* p0 = (g3 & 1) ? h1 : h0;
    ushort* p1 = (g3 & 1) ? h0 : h1;
    STEP2(t + 0, p0, p1, gA0, gA2, gB0, gB2);
    STEP2(t + 1, p1, p0, gA1, gA0, gB1, gB0);
    STEP2(t + 2, p0, p1, gA2, gA1, gB2, gB1);
  }
  // t=48 (even: read h0, write h1), t=49
  STEP2(48, h0, h1, gA0, gA2, gB0, gB2);
  STEP2(49, h1, h0, gA1, gA0, gB1, gB0);
}

// ---------------- fused pooling (reads bf16 OUTB) ----------------
__global__ __launch_bounds__(256) void pool_kernel(
    const int* __restrict__ h_iids, const ushort* __restrict__ OUTB,
    const float* __restrict__ W1, const float* __restrict__ b1,
    const ushort* __restrict__ W2T, const float* __restrict__ b2,
    const float* __restrict__ W3, const float* __restrict__ Wtr,
    const float* __restrict__ btr, ushort* __restrict__ GHT_bf) {
  const int b = blockIdx.x, tid = threadIdx.x;
  __shared__ float lh[128];
  __shared__ float q1[128];
  __shared__ float al[64];
  __shared__ float cat[256];

  if (tid < 128) {
    int cnt = 0;
    for (int s = 0; s < NB_S; s++) cnt += (h_iids[b * NB_S + s] != 0);
    int li = min(max(cnt - 1, 0), NB_S - 1);
    lh[tid] = bf2f(OUTB[((size_t)b * NB_S + li) * 128 + tid]);
  }
  __syncthreads();
  if (tid < 128) {
    float acc = b1[tid];
    for (int d = 0; d < 128; d++) acc += lh[d] * W1[(size_t)d * 128 + tid];
    q1[tid] = acc;
  }
  __syncthreads();

  {
    const int wv = tid >> 6, ln = tid & 63, lr = ln & 15, lg = ln >> 4;
    const int s0 = wv * 16;
    short8 zz = {0, 0, 0, 0, 0, 0, 0, 0};
    short8 afr[4];
    int srow = s0 + lr;
#pragma unroll
    for (int kf = 0; kf < 4; kf++)
      afr[kf] = (srow < NB_S)
                    ? *(const short8*)(OUTB + ((size_t)b * NB_S + srow) * 128 +
                                       lg * 8 + kf * 32)
                    : zz;
    float part[4] = {0.f, 0.f, 0.f, 0.f};
#pragma unroll
    for (int nf = 0; nf < 8; nf++) {
      const ushort* bb = W2T + (size_t)(nf * 16 + lr) * 128 + lg * 8;
      f32x4 acc = {};
#pragma unroll
      for (int kf = 0; kf < 4; kf++) {
        short8 bv = *(const short8*)(bb + kf * 32);
        acc = __builtin_amdgcn_mfma_f32_16x16x32_bf16(afr[kf], bv, acc, 0, 0, 0);
      }
      int c = nf * 16 + lr;
      float qc = q1[c] + b2[c];
      float w3 = W3[c];
#pragma unroll
      for (int r = 0; r < 4; r++)
        part[r] += w3 / (1.f + __expf(-(qc + acc[r])));
    }
#pragma unroll
    for (int r = 0; r < 4; r++) {
#pragma unroll
      for (int off = 1; off < 16; off <<= 1) part[r] += __shfl_xor(part[r], off);
      int s = s0 + lg * 4 + r;
      if (lr == 0 && s < NB_S) al[s] = part[r];
    }
  }
  __syncthreads();

  if (tid < 128) {
    float g = 0.f;
    for (int s = 0; s < NB_S; s++)
      g += al[s] * bf2f(OUTB[((size_t)b * NB_S + s) * 128 + tid]);
    cat[tid] = lh[tid];
    cat[128 + tid] = g;
  }
  __syncthreads();
  if (tid < 128) {
    float acc = btr[tid];
    for (int dd = 0; dd < 256; dd++) acc += cat[dd] * Wtr[(size_t)dd * 128 + tid];
    GHT_bf[b * 128 + tid] = f2bf(acc);
  }
}

// ---------------- logits = relu(GHT_bf @ EMB_BF^T) via MFMA ----------------
__global__ __launch_bounds__(256) void logits_mfma_kernel(
    const ushort* __restrict__ GHT_bf, const ushort* __restrict__ embB,
    float* __restrict__ out) {
  const int wv = threadIdx.x >> 6, ln = threadIdx.x & 63;
  const int lr = ln & 15, lg = ln >> 4;
  const int n0 = blockIdx.x * 128;
  const int m0 = wv * 64;

  short8 afr[4][4];
#pragma unroll
  for (int mf = 0; mf < 4; mf++) {
    const ushort* ab = GHT_bf + (size_t)(m0 + mf * 16 + lr) * 128 + lg * 8;
#pragma unroll
    for (int kf = 0; kf < 4; kf++) afr[mf][kf] = *(const short8*)(ab + kf * 32);
  }

  f32x4 acc[4][8] = {};
#pragma unroll
  for (int nf = 0; nf < 8; nf++) {
    int n = n0 + nf * 16 + lr;
    int nc = min(n, NB_NITEMS - 1);  // clamp load row; store is guarded
    const ushort* bb = embB + (size_t)nc * 128 + lg * 8;
    short8 b0_[4];
#pragma unroll
    for (int kf = 0; kf < 4; kf++) b0_[kf] = *(const short8*)(bb + kf * 32);
#pragma unroll
    for (int mf = 0; mf < 4; mf++)
#pragma unroll
      for (int kf = 0; kf < 4; kf++)
        acc[mf][nf] = __builtin_amdgcn_mfma_f32_16x16x32_bf16(
            afr[mf][kf], b0_[kf], acc[mf][nf], 0, 0, 0);
  }

#pragma unroll
  for (int mf = 0; mf < 4; mf++)
#pragma unroll
    for (int r = 0; r < 4; r++) {
      int m = m0 + mf * 16 + lg * 4 + r;
#pragma unroll
      for (int nf = 0; nf < 8; nf++) {
        int n = n0 + nf * 16 + lr;
        if (n < NB_NITEMS)
          out[(size_t)m * NB_NITEMS + n] = fmaxf(acc[mf][nf][r], 0.f);
      }
    }
}

extern "C" void kernel_launch(void* const* d_in, const int* in_sizes, int n_in,
                              void* d_out, int out_size, void* d_ws, size_t ws_size,
                              hipStream_t stream) {
  const int* h_iids = (const int*)d_in[0];
  const int* adj_e = (const int*)d_in[2];
  const int* adj_r = (const int*)d_in[3];
  const float* item_emb = (const float*)d_in[4];
  const float* rel_emb = (const float*)d_in[5];
  const float* Wa = (const float*)d_in[6];
  const float* Wt = (const float*)d_in[8];
  const float* bt = (const float*)d_in[9];
  const float* Wih = (const float*)d_in[10];
  const float* Whh = (const float*)d_in[11];
  const float* bih = (const float*)d_in[12];
  const float* bhh = (const float*)d_in[13];
  const float* W1 = (const float*)d_in[14];
  const float* b1 = (const float*)d_in[15];
  const float* W2 = (const float*)d_in[16];
  const float* b2 = (const float*)d_in[17];
  const float* W3 = (const float*)d_in[18];
  const float* Wtr = (const float*)d_in[19];
  const float* btr = (const float*)d_in[20];
  float* out = (float*)d_out;

  // ws layout (bytes), all 16B-aligned. ~84 MB total.
  char* w = (char*)d_ws;
  uint* EMB_BF = (uint*)w;                    w += 25600000;  // 100000x128 bf16
  uint* REL_BF = (uint*)w;                    w += 51200;     // 200x128 bf16
  ushort* WtT_bf = (ushort*)w;                w += 32768;     // [128][128]
  ushort* WihT_bf = (ushort*)w;               w += 98304;     // [384][128] scaled
  ushort* WhhT_bf = (ushort*)w;               w += 98304;     // [384][128] scaled
  ushort* W2T_bf = (ushort*)w;                w += 32768;     // [128][128]
  float* GIBIAS = (float*)w;                  w += 2048;      // 384 floats
  int* E0 = (int*)w;                          w += 409600;    // 102400 ints
  int* E2 = (int*)w;                          w += 3276800;   // 102400x8 ints
  int* RK = (int*)w;                          w += 3276800;   // 102400x8 ints
  int* RK1 = (int*)w;                         w += 409600;    // 12800x8 ints
  uint* NEIB_bf = (uint*)w;                   w += 26214400;  // 102400x128 bf16
  float* GI = (float*)w;                      w += 19660800;  // 12800x384 fp32
  ushort* OUTB = (ushort*)w;                  w += 3276800;   // 12800x128 bf16
  ushort* GHT_bf = (ushort*)w;                w += 65536;

  // ---- fused prep (1 launch; casts + flattened KG id tables) ----
  prep_kernel<<<7227, 256, 0, stream>>>(item_emb, rel_emb, Wt, Wih, Whh, W2,
                                        bih, bhh, h_iids, adj_e, adj_r, EMB_BF,
                                        REL_BF, WtT_bf, WihT_bf, WhhT_bf,
                                        W2T_bf, GIBIAS, E0, E2, RK, RK1);

  // ---- KG hops (hop0+Wt fused; hop1+Wt+Wih fused) ----
  hoplin_kernel<<<6400, 256, 0, stream>>>(E0, E2, RK, EMB_BF, REL_BF, Wa,
                                          WtT_bf, bt, (ushort*)NEIB_bf);
  hopgi_kernel<<<800, 256, 0, stream>>>(h_iids, RK1, EMB_BF, REL_BF, NEIB_bf,
                                        Wa, WtT_bf, bt, WihT_bf, GIBIAS, GI);

  // ---- GRU (8 blocks x 32 batches, 2 groups interleaved) + pooling ----
  gru_mfma_kernel<<<8, 512, 0, stream>>>(GI, WhhT_bf, bhh, OUTB);
  pool_kernel<<<256, 256, 0, stream>>>(h_iids, OUTB, W1, b1, W2T_bf, b2, W3,
                                       Wtr, btr, GHT_bf);

  // ---- logits ----
  logits_mfma_kernel<<<782, 256, 0, stream>>>(GHT_bf, (const ushort*)EMB_BF, out);
}

// Round 21
// 191.027 us; speedup vs baseline: 1.1720x; 1.1720x over previous
//
#include <hip/hip_runtime.h>
#include <hip/hip_bf16.h>
#include <math.h>

#define NB_B 256
#define NB_S 50
#define NB_NB 8
#define NB_D 128
#define NB_NITEMS 100000

#define C_RZ (-1.442695041f)   // -log2(e): sigmoid arg prescale
#define C_N (2.885390082f)     // 2*log2(e): tanh arg prescale

typedef __attribute__((ext_vector_type(8))) short short8;   // 8 x bf16 (4 VGPR)
typedef __attribute__((ext_vector_type(4))) float f32x4;    // MFMA acc
typedef unsigned int uint;
typedef unsigned short ushort;

// fp32 -> bf16 round-to-nearest-even
__device__ __forceinline__ ushort f2bf(float f) {
  union { float f; uint u; } v;
  v.f = f;
  return (ushort)((v.u + 0x7fffu + ((v.u >> 16) & 1u)) >> 16);
}
__device__ __forceinline__ uint packbf(float a, float b) {
  return (uint)f2bf(a) | ((uint)f2bf(b) << 16);
}
__device__ __forceinline__ float bflo(uint u) {
  union { uint u; float f; } v; v.u = u << 16; return v.f;
}
__device__ __forceinline__ float bfhi(uint u) {
  union { uint u; float f; } v; v.u = u & 0xffff0000u; return v.f;
}
__device__ __forceinline__ float bf2f(ushort u) {
  union { uint u; float f; } v; v.u = (uint)u << 16; return v.f;
}
__device__ __forceinline__ void unpack8(uint4 u, float* f) {
  f[0] = bflo(u.x); f[1] = bfhi(u.x);
  f[2] = bflo(u.y); f[3] = bfhi(u.y);
  f[4] = bflo(u.z); f[5] = bfhi(u.z);
  f[6] = bflo(u.w); f[7] = bfhi(u.w);
}

// ---------------- fused prep: casts + scaled transposes + GI bias + E0 ids ----------------
__device__ __forceinline__ void castf_body(const float* __restrict__ src,
                                           uint* __restrict__ dst, int i, int n8) {
  if (i >= n8) return;
  float4 a = ((const float4*)src)[2 * i];
  float4 b = ((const float4*)src)[2 * i + 1];
  uint4 o;
  o.x = packbf(a.x, a.y);
  o.y = packbf(a.z, a.w);
  o.z = packbf(b.x, b.y);
  o.w = packbf(b.z, b.w);
  ((uint4*)dst)[i] = o;
}
template <int CO, bool SCALED>
__device__ __forceinline__ void castT_body(const float* __restrict__ W,
                                           ushort* __restrict__ WT, int idx) {
  if (idx >= 128 * CO) return;
  int n = idx >> 7, k = idx & 127;
  float v = W[(size_t)k * CO + n];
  if (SCALED) v *= (n < 256 ? C_RZ : C_N);
  WT[idx] = f2bf(v);
}
__global__ __launch_bounds__(256) void prep_kernel(
    const float* __restrict__ item_emb, const float* __restrict__ rel_emb,
    const float* __restrict__ Wt, const float* __restrict__ Wih,
    const float* __restrict__ Whh, const float* __restrict__ W2,
    const float* __restrict__ bih, const float* __restrict__ bhh,
    const int* __restrict__ h_iids, const int* __restrict__ adj_e,
    uint* __restrict__ EMB_BF, uint* __restrict__ REL_BF,
    ushort* __restrict__ WtT, ushort* __restrict__ WihT,
    ushort* __restrict__ WhhT, ushort* __restrict__ W2T,
    float* __restrict__ GIBIAS, int* __restrict__ E0) {
  int bx = blockIdx.x, tid = threadIdx.x;
  if (bx < 6250) {
    castf_body(item_emb, EMB_BF, bx * 256 + tid, 1600000);
  } else if (bx < 6263) {
    castf_body(rel_emb, REL_BF, (bx - 6250) * 256 + tid, 3200);
  } else if (bx < 6327) {
    castT_body<128, false>(Wt, WtT, (bx - 6263) * 256 + tid);
  } else if (bx < 6519) {
    castT_body<384, true>(Wih, WihT, (bx - 6327) * 256 + tid);
  } else if (bx < 6711) {
    castT_body<384, true>(Whh, WhhT, (bx - 6519) * 256 + tid);
  } else if (bx < 6775) {
    castT_body<128, false>(W2, W2T, (bx - 6711) * 256 + tid);
  } else if (bx < 6776) {
    int idx = tid;
    if (idx < 256) {
      GIBIAS[idx] = C_RZ * (bih[idx] + bhh[idx]);
    }
  } else if (bx < 6777) {
    int idx = 256 + tid;
    if (idx < 384) GIBIAS[idx] = C_N * bih[idx];
  } else {
    int p = (bx - 6777) * 256 + tid;
    if (p < NB_B * NB_S * NB_NB) {
      int b = p / (NB_S * NB_NB);
      int m = p % (NB_S * NB_NB);
      int h = h_iids[b * NB_S + (m >> 3)];
      E0[p] = adj_e[h * NB_NB + (m & 7)];
    }
  }
}

// ---------------- hop pair: 16-lane group, 8 dims/lane, multi-value reduce ----------------
__device__ __forceinline__ uint4 hop_pair4(
    int e_self, int q, int p, const int* __restrict__ adj_e,
    const int* __restrict__ adj_r, const uint* __restrict__ embB,
    const uint* __restrict__ relB, const uint* __restrict__ neibB,
    const float* __restrict__ Wa, float* __restrict__ alds) {
  uint4 us = ((const uint4*)(embB + (size_t)e_self * 64))[q];
  float s[8], wa[8], sw[8];
  unpack8(us, s);
  *(float4*)&wa[0] = ((const float4*)Wa)[q * 2];
  *(float4*)&wa[4] = ((const float4*)Wa)[q * 2 + 1];
#pragma unroll
  for (int d = 0; d < 8; d++) sw[d] = s[d] * wa[d];

  int4 ra = ((const int4*)(adj_r + (size_t)e_self * 8))[0];
  int4 rb = ((const int4*)(adj_r + (size_t)e_self * 8))[1];
  int rk[8] = {ra.x, ra.y, ra.z, ra.w, rb.x, rb.y, rb.z, rb.w};

  uint4 nbp[8];
  if (neibB == nullptr) {
    int4 ea = ((const int4*)(adj_e + (size_t)e_self * 8))[0];
    int4 eb = ((const int4*)(adj_e + (size_t)e_self * 8))[1];
    int e2[8] = {ea.x, ea.y, ea.z, ea.w, eb.x, eb.y, eb.z, eb.w};
#pragma unroll
    for (int k = 0; k < 8; k++)
      nbp[k] = ((const uint4*)(embB + (size_t)e2[k] * 64))[q];
  } else {
#pragma unroll
    for (int k = 0; k < 8; k++)
      nbp[k] = ((const uint4*)(neibB + ((size_t)p * 8 + k) * 64))[q];
  }

  float t[8];
#pragma unroll
  for (int k = 0; k < 8; k++) {
    uint4 ur = ((const uint4*)(relB + (size_t)rk[k] * 64))[q];
    float rr[8], nb[8];
    unpack8(ur, rr);
    unpack8(nbp[k], nb);
    float tt = 0.f;
#pragma unroll
    for (int d = 0; d < 8; d++) tt = fmaf(sw[d] * rr[d], nb[d], tt);
    t[k] = tt;
  }

  // multi-value halving butterfly within 16 lanes: 8 values -> 1 per lane
  bool b0 = (q & 1), b1 = (q & 2), b2 = (q & 4);
  float a4[4];
#pragma unroll
  for (int i = 0; i < 4; i++) {
    float send = b0 ? t[i] : t[4 + i];
    float recv = __shfl_xor(send, 1);
    a4[i] = (b0 ? t[4 + i] : t[i]) + recv;
  }
  float a2[2];
#pragma unroll
  for (int i = 0; i < 2; i++) {
    float send = b1 ? a4[i] : a4[2 + i];
    float recv = __shfl_xor(send, 2);
    a2[i] = (b1 ? a4[2 + i] : a4[i]) + recv;
  }
  float send1 = b2 ? a2[0] : a2[1];
  float recv1 = __shfl_xor(send1, 4);
  float c = (b2 ? a2[1] : a2[0]) + recv1;
  c += __shfl_xor(c, 8);  // att[k*], k* = (q&1)*4 + (q&2) + ((q&4)>>2)

  // softmax over 8 k-classes (|att|<=~0.04: no max-subtraction needed)
  float e = __expf(c);
  float den = e;
  den += __shfl_xor(den, 1);
  den += __shfl_xor(den, 2);
  den += __shfl_xor(den, 4);
  float alpha = e * __builtin_amdgcn_rcpf(den);

  // broadcast alphas via per-group LDS slot (wave-synchronous)
  int kstar = (q & 1) * 4 + (q & 2) + ((q & 4) >> 2);
  if (q < 8) alds[kstar] = alpha;
  asm volatile("s_waitcnt lgkmcnt(0)" ::: "memory");
  float a8[8];
  *(float4*)&a8[0] = ((const float4*)alds)[0];
  *(float4*)&a8[4] = ((const float4*)alds)[1];

  float x[8];
#pragma unroll
  for (int d = 0; d < 8; d++) x[d] = s[d];
#pragma unroll
  for (int k = 0; k < 8; k++) {
    float nb[8];
    unpack8(nbp[k], nb);
#pragma unroll
    for (int d = 0; d < 8; d++) x[d] = fmaf(a8[k], nb[d], x[d]);
  }
  uint4 o;
  o.x = packbf(x[0], x[1]);
  o.y = packbf(x[2], x[3]);
  o.z = packbf(x[4], x[5]);
  o.w = packbf(x[6], x[7]);
  return o;
}

// ---------------- fused hop0 + lin0: 16 pairs/block, E0-precomputed ids ----------------
__global__ __launch_bounds__(256) void hoplin_kernel(
    const int* __restrict__ E0, const int* __restrict__ adj_e,
    const int* __restrict__ adj_r, const uint* __restrict__ embB,
    const uint* __restrict__ relB, const float* __restrict__ Wa,
    const ushort* __restrict__ WtT, const float* __restrict__ bt,
    ushort* __restrict__ NEIB) {
  __shared__ ushort X0s[16 * 128];  // XOR-swizzled
  __shared__ float als[16][8];
  const int bx = blockIdx.x;
  const int wv = threadIdx.x >> 6, ln = threadIdx.x & 63;
  const int g = ln >> 4, q = ln & 15;
  const int lp = wv * 4 + g;  // local pair 0..15
  const int p = bx * 16 + lp;

  int e_self = E0[p];
  uint4 o = hop_pair4(e_self, q, p, adj_e, adj_r, embB, relB, nullptr, Wa,
                      als[lp]);
  {
    int byte = (lp * 256 + q * 16) ^ ((lp & 7) << 4);
    *(uint4*)((char*)X0s + byte) = o;
  }
  __syncthreads();

  // MFMA: NEIB[16 rows][128] = X0s @ WtT^T + bt; wave wv covers cols [32wv,32wv+32)
  const int lr = ln & 15, lg = ln >> 4;
  short8 afr[4];
#pragma unroll
  for (int kf = 0; kf < 4; kf++) {
    int byte = (lr * 256 + lg * 16 + kf * 64) ^ ((lr & 7) << 4);
    afr[kf] = *(const short8*)((const char*)X0s + byte);
  }
  f32x4 acc[2] = {};
#pragma unroll
  for (int nf = 0; nf < 2; nf++) {
    int n = (wv * 2 + nf) * 16 + lr;
    const ushort* bb = WtT + (size_t)n * 128 + lg * 8;
#pragma unroll
    for (int kf = 0; kf < 4; kf++) {
      short8 bv = *(const short8*)(bb + kf * 32);
      acc[nf] = __builtin_amdgcn_mfma_f32_16x16x32_bf16(afr[kf], bv, acc[nf],
                                                        0, 0, 0);
    }
  }
#pragma unroll
  for (int nf = 0; nf < 2; nf++) {
    int n = (wv * 2 + nf) * 16 + lr;
    float bv = bt[n];
#pragma unroll
    for (int r = 0; r < 4; r++) {
      int mg = bx * 16 + lg * 4 + r;
      NEIB[(size_t)mg * 128 + n] = f2bf(acc[nf][r] + bv);
    }
  }
}

// ---------------- fused hop1 + SEQ GEMM + GI GEMM ----------------
__global__ __launch_bounds__(256) void hopgi_kernel(
    const int* __restrict__ h_iids, const int* __restrict__ adj_e,
    const int* __restrict__ adj_r, const uint* __restrict__ embB,
    const uint* __restrict__ relB, const uint* __restrict__ neibB,
    const float* __restrict__ Wa, const ushort* __restrict__ WtT,
    const float* __restrict__ bt, const ushort* __restrict__ WihT,
    const float* __restrict__ GIBIAS, float* __restrict__ GI) {
  __shared__ ushort X1s[16 * 128];  // XOR-swizzled
  __shared__ ushort SEQs[16 * 128]; // XOR-swizzled
  __shared__ float als[16][8];
  const int wv = threadIdx.x >> 6, ln = threadIdx.x & 63;
  const int g = ln >> 4, q = ln & 15;
  const int lp = wv * 4 + g;  // local pair 0..15
  const int p = blockIdx.x * 16 + lp;

  int e_self = h_iids[p];
  uint4 o = hop_pair4(e_self, q, p, adj_e, adj_r, embB, relB, neibB, Wa, als[lp]);
  {
    int byte = (lp * 256 + q * 16) ^ ((lp & 7) << 4);
    *(uint4*)((char*)X1s + byte) = o;
  }
  __syncthreads();

  const int lr = ln & 15, lg = ln >> 4;
  // phase 2: SEQ = X1 @ WtT + bt; wave covers cols [wv*32, wv*32+32)
  {
    short8 afr[4];
#pragma unroll
    for (int kf = 0; kf < 4; kf++) {
      int byte = (lr * 256 + lg * 16 + kf * 64) ^ ((lr & 7) << 4);
      afr[kf] = *(const short8*)((const char*)X1s + byte);
    }
    f32x4 acc[2] = {};
#pragma unroll
    for (int nf = 0; nf < 2; nf++) {
      int n = (wv * 2 + nf) * 16 + lr;
      const ushort* bb = WtT + (size_t)n * 128 + lg * 8;
#pragma unroll
      for (int kf = 0; kf < 4; kf++) {
        short8 b = *(const short8*)(bb + kf * 32);
        acc[nf] = __builtin_amdgcn_mfma_f32_16x16x32_bf16(afr[kf], b, acc[nf],
                                                          0, 0, 0);
      }
    }
#pragma unroll
    for (int nf = 0; nf < 2; nf++) {
      int n = (wv * 2 + nf) * 16 + lr;
      float bv = bt[n];
#pragma unroll
      for (int r = 0; r < 4; r++) {
        int m = lg * 4 + r;
        int byte = (m * 256 + n * 2) ^ ((m & 7) << 4);
        *(ushort*)((char*)SEQs + byte) = f2bf(acc[nf][r] + bv);
      }
    }
  }
  __syncthreads();

  // phase 3: GI = SEQ @ WihT + GIBIAS; wave covers cols [wv*96, wv*96+96)
  {
    short8 sfr[4];
#pragma unroll
    for (int kf = 0; kf < 4; kf++) {
      int byte = (lr * 256 + lg * 16 + kf * 64) ^ ((lr & 7) << 4);
      sfr[kf] = *(const short8*)((const char*)SEQs + byte);
    }
#pragma unroll
    for (int i = 0; i < 6; i++) {
      int n = (wv * 6 + i) * 16 + lr;
      const ushort* bb = WihT + (size_t)n * 128 + lg * 8;
      f32x4 a2 = {};
#pragma unroll
      for (int kf = 0; kf < 4; kf++) {
        short8 b = *(const short8*)(bb + kf * 32);
        a2 = __builtin_amdgcn_mfma_f32_16x16x32_bf16(sfr[kf], b, a2, 0, 0, 0);
      }
      float bv = GIBIAS[n];
#pragma unroll
      for (int r = 0; r < 4; r++) {
        int m = lg * 4 + r;
        GI[(size_t)(blockIdx.x * 16 + m) * 384 + n] = a2[r] + bv;
      }
    }
  }
}

// ---------------- GRU: lane-local gates, depth-3 pipeline, exp2 prescaled ----------------
__global__ __launch_bounds__(512) void gru_mfma_kernel(
    const float* __restrict__ GI, const ushort* __restrict__ WhhT_bf,
    const float* __restrict__ bhh, ushort* __restrict__ OUTB) {
  const int b0 = blockIdx.x * 16;
  const int tid = threadIdx.x;
  const int w = tid >> 6, ln = tid & 63;
  const int lr = ln & 15, lg = ln >> 4;
  const int j = w * 16 + lr;

  __shared__ ushort hA[16 * 128];
  __shared__ ushort hB[16 * 128];

  short8 bfr[3][4];
#pragma unroll
  for (int g = 0; g < 3; g++) {
    const ushort* bb = WhhT_bf + (size_t)(g * 128 + j) * 128 + lg * 8;
#pragma unroll
    for (int kf = 0; kf < 4; kf++) bfr[g][kf] = *(const short8*)(bb + kf * 32);
  }
  const float bhn = C_N * bhh[256 + j];

  float h_reg[4] = {0.f, 0.f, 0.f, 0.f};

  {
    uint* hz = (uint*)hA;
#pragma unroll
    for (int i = tid; i < 1024; i += 512) hz[i] = 0;
  }
  __syncthreads();

  float girA[4][3], girB[4][3], girC[4][3], girD[4][3];
#pragma unroll
  for (int r = 0; r < 4; r++) {
    const float* g0 = GI + ((size_t)(b0 + lg * 4 + r) * NB_S + 0) * 384 + j;
    girA[r][0] = g0[0]; girA[r][1] = g0[128]; girA[r][2] = g0[256];
    const float* g1 = GI + ((size_t)(b0 + lg * 4 + r) * NB_S + 1) * 384 + j;
    girB[r][0] = g1[0]; girB[r][1] = g1[128]; girB[r][2] = g1[256];
    const float* g2 = GI + ((size_t)(b0 + lg * 4 + r) * NB_S + 2) * 384 + j;
    girC[r][0] = g2[0]; girC[r][1] = g2[128]; girC[r][2] = g2[256];
  }

  auto STEP = [&](int t, ushort* hRead, ushort* hWrite, float (&cur)[4][3],
                  float (&pre3)[4][3]) {
    if (t + 3 < NB_S) {
#pragma unroll
      for (int r = 0; r < 4; r++) {
        const float* g = GI + ((size_t)(b0 + lg * 4 + r) * NB_S + (t + 3)) * 384 + j;
        pre3[r][0] = g[0]; pre3[r][1] = g[128]; pre3[r][2] = g[256];
      }
    }
    __builtin_amdgcn_sched_barrier(0);
    short8 afr[4];
#pragma unroll
    for (int kf = 0; kf < 4; kf++) {
      int byte = (lr * 256 + kf * 64 + lg * 16) ^ ((lr & 7) << 4);
      afr[kf] = *(const short8*)((const char*)hRead + byte);
    }
    f32x4 acc[3] = {};
#pragma unroll
    for (int g = 0; g < 3; g++)
#pragma unroll
      for (int kf = 0; kf < 4; kf++)
        acc[g] = __builtin_amdgcn_mfma_f32_16x16x32_bf16(afr[kf], bfr[g][kf],
                                                         acc[g], 0, 0, 0);
#pragma unroll
    for (int r = 0; r < 4; r++) {
      int b = lg * 4 + r;
      float rg = __builtin_amdgcn_rcpf(
          1.f + __builtin_amdgcn_exp2f(cur[r][0] + acc[0][r]));
      float ze = __builtin_amdgcn_exp2f(cur[r][1] + acc[1][r]);
      float xp = cur[r][2] + rg * (bhn + acc[2][r]);
      float e2 = __builtin_amdgcn_exp2f(xp);
      float n = 1.f - 2.f * __builtin_amdgcn_rcpf(e2 + 1.f);
      float h2 = n + (h_reg[r] - n) * __builtin_amdgcn_rcpf(1.f + ze);
      h_reg[r] = h2;
      ushort hb = f2bf(h2);
      OUTB[((size_t)(b0 + b) * NB_S + t) * 128 + j] = hb;
      int byte = (b * 256 + j * 2) ^ ((b & 7) << 4);
      *(ushort*)((char*)hWrite + byte) = hb;
    }
    asm volatile("s_waitcnt lgkmcnt(0)" ::: "memory");
    __builtin_amdgcn_s_barrier();
  };

  for (int g4 = 0; g4 < 12; g4++) {
    int t = g4 * 4;
    STEP(t + 0, hA, hB, girA, girD);
    STEP(t + 1, hB, hA, girB, girA);
    STEP(t + 2, hA, hB, girC, girB);
    STEP(t + 3, hB, hA, girD, girC);
  }
  STEP(48, hA, hB, girA, girD);
  STEP(49, hB, hA, girB, girA);
}

// ---------------- fused pooling (reads bf16 OUTB) ----------------
__global__ __launch_bounds__(256) void pool_kernel(
    const int* __restrict__ h_iids, const ushort* __restrict__ OUTB,
    const float* __restrict__ W1, const float* __restrict__ b1,
    const ushort* __restrict__ W2T, const float* __restrict__ b2,
    const float* __restrict__ W3, const float* __restrict__ Wtr,
    const float* __restrict__ btr, ushort* __restrict__ GHT_bf) {
  const int b = blockIdx.x, tid = threadIdx.x;
  __shared__ float lh[128];
  __shared__ float q1[128];
  __shared__ float al[64];
  __shared__ float cat[256];

  if (tid < 128) {
    int cnt = 0;
    for (int s = 0; s < NB_S; s++) cnt += (h_iids[b * NB_S + s] != 0);
    int li = min(max(cnt - 1, 0), NB_S - 1);
    lh[tid] = bf2f(OUTB[((size_t)b * NB_S + li) * 128 + tid]);
  }
  __syncthreads();
  if (tid < 128) {
    float acc = b1[tid];
    for (int d = 0; d < 128; d++) acc += lh[d] * W1[(size_t)d * 128 + tid];
    q1[tid] = acc;
  }
  __syncthreads();

  {
    const int wv = tid >> 6, ln = tid & 63, lr = ln & 15, lg = ln >> 4;
    const int s0 = wv * 16;
    short8 zz = {0, 0, 0, 0, 0, 0, 0, 0};
    short8 afr[4];
    int srow = s0 + lr;
#pragma unroll
    for (int kf = 0; kf < 4; kf++)
      afr[kf] = (srow < NB_S)
                    ? *(const short8*)(OUTB + ((size_t)b * NB_S + srow) * 128 +
                                       lg * 8 + kf * 32)
                    : zz;
    float part[4] = {0.f, 0.f, 0.f, 0.f};
#pragma unroll
    for (int nf = 0; nf < 8; nf++) {
      const ushort* bb = W2T + (size_t)(nf * 16 + lr) * 128 + lg * 8;
      f32x4 acc = {};
#pragma unroll
      for (int kf = 0; kf < 4; kf++) {
        short8 bv = *(const short8*)(bb + kf * 32);
        acc = __builtin_amdgcn_mfma_f32_16x16x32_bf16(afr[kf], bv, acc, 0, 0, 0);
      }
      int c = nf * 16 + lr;
      float qc = q1[c] + b2[c];
      float w3 = W3[c];
#pragma unroll
      for (int r = 0; r < 4; r++)
        part[r] += w3 / (1.f + __expf(-(qc + acc[r])));
    }
#pragma unroll
    for (int r = 0; r < 4; r++) {
#pragma unroll
      for (int off = 1; off < 16; off <<= 1) part[r] += __shfl_xor(part[r], off);
      int s = s0 + lg * 4 + r;
      if (lr == 0 && s < NB_S) al[s] = part[r];
    }
  }
  __syncthreads();

  if (tid < 128) {
    float g = 0.f;
    for (int s = 0; s < NB_S; s++)
      g += al[s] * bf2f(OUTB[((size_t)b * NB_S + s) * 128 + tid]);
    cat[tid] = lh[tid];
    cat[128 + tid] = g;
  }
  __syncthreads();
  if (tid < 128) {
    float acc = btr[tid];
    for (int dd = 0; dd < 256; dd++) acc += cat[dd] * Wtr[(size_t)dd * 128 + tid];
    GHT_bf[b * 128 + tid] = f2bf(acc);
  }
}

// ---------------- logits = relu(GHT_bf @ EMB_BF^T) via MFMA ----------------
// 782 blocks x 256 threads; wave wv covers m in [wv*64, wv*64+64), n in
// [n0, n0+128). Per (m-row, wave) the 8 nf stores form a 512B contiguous run.
__global__ __launch_bounds__(256) void logits_mfma_kernel(
    const ushort* __restrict__ GHT_bf, const ushort* __restrict__ embB,
    float* __restrict__ out) {
  const int wv = threadIdx.x >> 6, ln = threadIdx.x & 63;
  const int lr = ln & 15, lg = ln >> 4;
  const int n0 = blockIdx.x * 128;
  const int m0 = wv * 64;

  short8 afr[4][4];
#pragma unroll
  for (int mf = 0; mf < 4; mf++) {
    const ushort* ab = GHT_bf + (size_t)(m0 + mf * 16 + lr) * 128 + lg * 8;
#pragma unroll
    for (int kf = 0; kf < 4; kf++) afr[mf][kf] = *(const short8*)(ab + kf * 32);
  }

  f32x4 acc[4][8] = {};
#pragma unroll
  for (int nf = 0; nf < 8; nf++) {
    int n = n0 + nf * 16 + lr;
    int nc = min(n, NB_NITEMS - 1);  // clamp load row; store is guarded
    const ushort* bb = embB + (size_t)nc * 128 + lg * 8;
    short8 b0_[4];
#pragma unroll
    for (int kf = 0; kf < 4; kf++) b0_[kf] = *(const short8*)(bb + kf * 32);
#pragma unroll
    for (int mf = 0; mf < 4; mf++)
#pragma unroll
      for (int kf = 0; kf < 4; kf++)
        acc[mf][nf] = __builtin_amdgcn_mfma_f32_16x16x32_bf16(
            afr[mf][kf], b0_[kf], acc[mf][nf], 0, 0, 0);
  }

#pragma unroll
  for (int mf = 0; mf < 4; mf++)
#pragma unroll
    for (int r = 0; r < 4; r++) {
      int m = m0 + mf * 16 + lg * 4 + r;
#pragma unroll
      for (int nf = 0; nf < 8; nf++) {
        int n = n0 + nf * 16 + lr;
        if (n < NB_NITEMS)
          out[(size_t)m * NB_NITEMS + n] = fmaxf(acc[mf][nf][r], 0.f);
      }
    }
}

extern "C" void kernel_launch(void* const* d_in, const int* in_sizes, int n_in,
                              void* d_out, int out_size, void* d_ws, size_t ws_size,
                              hipStream_t stream) {
  const int* h_iids = (const int*)d_in[0];
  const int* adj_e = (const int*)d_in[2];
  const int* adj_r = (const int*)d_in[3];
  const float* item_emb = (const float*)d_in[4];
  const float* rel_emb = (const float*)d_in[5];
  const float* Wa = (const float*)d_in[6];
  const float* Wt = (const float*)d_in[8];
  const float* bt = (const float*)d_in[9];
  const float* Wih = (const float*)d_in[10];
  const float* Whh = (const float*)d_in[11];
  const float* bih = (const float*)d_in[12];
  const float* bhh = (const float*)d_in[13];
  const float* W1 = (const float*)d_in[14];
  const float* b1 = (const float*)d_in[15];
  const float* W2 = (const float*)d_in[16];
  const float* b2 = (const float*)d_in[17];
  const float* W3 = (const float*)d_in[18];
  const float* Wtr = (const float*)d_in[19];
  const float* btr = (const float*)d_in[20];
  float* out = (float*)d_out;

  // ws layout (bytes), all 16B-aligned. ~77 MB total.
  char* w = (char*)d_ws;
  uint* EMB_BF = (uint*)w;                    w += 25600000;  // 100000x128 bf16
  uint* REL_BF = (uint*)w;                    w += 51200;     // 200x128 bf16
  ushort* WtT_bf = (ushort*)w;                w += 32768;     // [128][128]
  ushort* WihT_bf = (ushort*)w;               w += 98304;     // [384][128] scaled
  ushort* WhhT_bf = (ushort*)w;               w += 98304;     // [384][128] scaled
  ushort* W2T_bf = (ushort*)w;                w += 32768;     // [128][128]
  float* GIBIAS = (float*)w;                  w += 2048;      // 384 floats
  int* E0 = (int*)w;                          w += 409600;    // 102400 ints
  uint* NEIB_bf = (uint*)w;                   w += 26214400;  // 102400x128 bf16
  float* GI = (float*)w;                      w += 19660800;  // 12800x384 fp32
  ushort* OUTB = (ushort*)w;                  w += 3276800;   // 12800x128 bf16
  ushort* GHT_bf = (ushort*)w;                w += 65536;

  // ---- fused prep (1 launch; +400 blocks for E0 ids) ----
  prep_kernel<<<7177, 256, 0, stream>>>(item_emb, rel_emb, Wt, Wih, Whh, W2,
                                        bih, bhh, h_iids, adj_e, EMB_BF, REL_BF,
                                        WtT_bf, WihT_bf, WhhT_bf, W2T_bf,
                                        GIBIAS, E0);

  // ---- KG hops (hop0+Wt fused; hop1+Wt+Wih fused) ----
  hoplin_kernel<<<6400, 256, 0, stream>>>(E0, adj_e, adj_r, EMB_BF, REL_BF,
                                          Wa, WtT_bf, bt, (ushort*)NEIB_bf);
  hopgi_kernel<<<800, 256, 0, stream>>>(h_iids, adj_e, adj_r, EMB_BF, REL_BF,
                                        NEIB_bf, Wa, WtT_bf, bt, WihT_bf,
                                        GIBIAS, GI);

  // ---- GRU + fused pooling ----
  gru_mfma_kernel<<<16, 512, 0, stream>>>(GI, WhhT_bf, bhh, OUTB);
  pool_kernel<<<256, 256, 0, stream>>>(h_iids, OUTB, W1, b1, W2T_bf, b2, W3,
                                       Wtr, btr, GHT_bf);

  // ---- logits ----
  logits_mfma_kernel<<<782, 256, 0, stream>>>(GHT_bf, (const ushort*)EMB_BF, out);
}